// Round 6
// baseline (271.417 us; speedup 1.0000x reference)
//
#include <hip/hip_runtime.h>
#include <math.h>

// Problem constants: B=4, T=1024, C=1024, H=16, DH=64
namespace {
constexpr int NB  = 4;
constexpr int NT  = 1024;
constexpr int NC  = 1024;
constexpr int NH  = 16;
constexpr int MT  = NB * NT;   // 4096
constexpr int KW8 = NC / 4;    // 256 u32 (u8 x4) per row
}

typedef _Float16 f16x8 __attribute__((ext_vector_type(8)));
typedef float f32x4 __attribute__((ext_vector_type(4)));

__device__ __forceinline__ unsigned sad8(unsigned a, unsigned b, unsigned c) {
  unsigned d;
  asm("v_sad_u8 %0, %1, %2, %3" : "=v"(d) : "v"(a), "v"(b), "v"(c));
  return d;
}

__device__ __forceinline__ unsigned sad16(unsigned a, unsigned b, unsigned c) {
#if __has_builtin(__builtin_amdgcn_sad_u16)
  return __builtin_amdgcn_sad_u16(a, b, c);
#else
  unsigned d;
  asm("v_sad_u16 %0, %1, %2, %3" : "=v"(d) : "v"(a), "v"(b), "v"(c));
  return d;
#endif
}

// quantize pair to u16 counts at 8192/unit, offset 32768 (for attention SAD)
__device__ __forceinline__ unsigned packq8k(float a, float b) {
  float fa = fminf(fmaxf(fmaf(a, 8192.0f, 32768.5f), 0.0f), 65535.0f);
  float fb = fminf(fmaxf(fmaf(b, 8192.0f, 32768.5f), 0.0f), 65535.0f);
  return (unsigned)fa | ((unsigned)fb << 16);
}

__device__ __forceinline__ unsigned short f16u(float x) {
  _Float16 h = (_Float16)x;
  return __builtin_bit_cast(unsigned short, h);
}

// ---------------- tanh + u8 quantize (8 floats -> 2 packed u32) ----------------
__global__ __launch_bounds__(256) void k_tanhq8(const float* __restrict__ in,
                                                unsigned* __restrict__ out, int n8) {
  int i = blockIdx.x * blockDim.x + threadIdx.x;
  if (i >= n8) return;
  const float4* in4 = reinterpret_cast<const float4*>(in);
  float4 v0 = in4[2 * i], v1 = in4[2 * i + 1];
  float t[8] = {v0.x, v0.y, v0.z, v0.w, v1.x, v1.y, v1.z, v1.w};
  unsigned q[8];
#pragma unroll
  for (int j = 0; j < 8; ++j)
    q[j] = (unsigned)fmaf(tanhf(t[j]), 127.5f, 128.0f);  // 0..255
  uint2 o = {q[0] | (q[1] << 8) | (q[2] << 16) | (q[3] << 24),
             q[4] | (q[5] << 8) | (q[6] << 16) | (q[7] << 24)};
  reinterpret_cast<uint2*>(out)[i] = o;
}

// ---------------- fp32 -> f16 convert ----------------
__global__ __launch_bounds__(256) void k_cvt16(const float* __restrict__ in,
                                               unsigned short* __restrict__ out, int n8) {
  int i = blockIdx.x * blockDim.x + threadIdx.x;
  if (i >= n8) return;
  const float4* in4 = reinterpret_cast<const float4*>(in);
  float4 v0 = in4[2 * i], v1 = in4[2 * i + 1];
  ushort4 o0 = {f16u(v0.x), f16u(v0.y), f16u(v0.z), f16u(v0.w)};
  ushort4 o1 = {f16u(v1.x), f16u(v1.y), f16u(v1.z), f16u(v1.w)};
  reinterpret_cast<ushort4*>(out)[2 * i] = o0;
  reinterpret_cast<ushort4*>(out)[2 * i + 1] = o1;
}

// ---------------- u8 SAD projection (unchanged from R5) ----------------
__global__ __launch_bounds__(256) void k_sadproj8(const unsigned* __restrict__ Aq,
                                                  const unsigned* __restrict__ Bq,
                                                  const float* __restrict__ g0,
                                                  const float* __restrict__ g1,
                                                  const float* __restrict__ g2,
                                                  unsigned* __restrict__ qq_hm,
                                                  unsigned* __restrict__ kq_hm,
                                                  unsigned short* __restrict__ vh_dm) {
  __shared__ unsigned As[16][132];
  __shared__ unsigned Bs[16][132];

  const int tid = threadIdx.x;
  const int z = blockIdx.z;
  const unsigned* Bz = Bq + (size_t)z * NC * KW8;
  const float* G = (z == 0) ? g0 : ((z == 1) ? g1 : g2);
  const int m0 = blockIdx.y * 128;
  const int n0 = blockIdx.x * 128;
  const int ty = tid >> 4;
  const int tx = tid & 15;

  unsigned acc[8][8];
#pragma unroll
  for (int i = 0; i < 8; ++i)
#pragma unroll
    for (int j = 0; j < 8; ++j) acc[i][j] = 0u;

  const int tt = tid & 127;
  const int duq = tt & 3;
  const int r0 = (tt >> 2) * 4;
  const bool doB = (tid >= 128);
  const unsigned* Src = doB ? (Bz + (size_t)n0 * KW8) : (Aq + (size_t)m0 * KW8);

  for (int s = 0; s < 16; ++s) {
    __syncthreads();
    uint4 rv[4];
#pragma unroll
    for (int k2 = 0; k2 < 4; ++k2)
      rv[k2] = *reinterpret_cast<const uint4*>(Src + (size_t)(r0 + k2) * KW8 + s * 16 + duq * 4);
    uint4 w0 = {rv[0].x, rv[1].x, rv[2].x, rv[3].x};
    uint4 w1 = {rv[0].y, rv[1].y, rv[2].y, rv[3].y};
    uint4 w2 = {rv[0].z, rv[1].z, rv[2].z, rv[3].z};
    uint4 w3 = {rv[0].w, rv[1].w, rv[2].w, rv[3].w};
    if (doB) {
      *reinterpret_cast<uint4*>(&Bs[duq * 4 + 0][r0]) = w0;
      *reinterpret_cast<uint4*>(&Bs[duq * 4 + 1][r0]) = w1;
      *reinterpret_cast<uint4*>(&Bs[duq * 4 + 2][r0]) = w2;
      *reinterpret_cast<uint4*>(&Bs[duq * 4 + 3][r0]) = w3;
    } else {
      *reinterpret_cast<uint4*>(&As[duq * 4 + 0][r0]) = w0;
      *reinterpret_cast<uint4*>(&As[duq * 4 + 1][r0]) = w1;
      *reinterpret_cast<uint4*>(&As[duq * 4 + 2][r0]) = w2;
      *reinterpret_cast<uint4*>(&As[duq * 4 + 3][r0]) = w3;
    }
    __syncthreads();

#pragma unroll 4
    for (int du = 0; du < 16; ++du) {
      uint4 alo = *reinterpret_cast<const uint4*>(&As[du][ty * 4]);
      uint4 ahi = *reinterpret_cast<const uint4*>(&As[du][64 + ty * 4]);
      uint4 blo = *reinterpret_cast<const uint4*>(&Bs[du][tx * 4]);
      uint4 bhi = *reinterpret_cast<const uint4*>(&Bs[du][64 + tx * 4]);
      unsigned av[8] = {alo.x, alo.y, alo.z, alo.w, ahi.x, ahi.y, ahi.z, ahi.w};
      unsigned bv[8] = {blo.x, blo.y, blo.z, blo.w, bhi.x, bhi.y, bhi.z, bhi.w};
#pragma unroll
      for (int i = 0; i < 8; ++i)
#pragma unroll
        for (int j = 0; j < 8; ++j) acc[i][j] = sad8(av[i], bv[j], acc[i][j]);
    }
  }

  const float invS = 1.0f / (1024.0f * 127.5f);
  const int bI = m0 >> 10;
  const int tBase = m0 & 1023;
  const int hl = n0 >> 6;
  float gl[8];
#pragma unroll
  for (int j = 0; j < 4; ++j) {
    gl[j]     = G[n0 + tx * 4 + j];
    gl[j + 4] = G[n0 + 64 + tx * 4 + j];
  }

  if (z < 2) {
    unsigned* dst = (z == 0) ? qq_hm : kq_hm;
#pragma unroll
    for (int i = 0; i < 8; ++i) {
      int rr = (i < 4) ? (ty * 4 + i) : (64 + ty * 4 + (i - 4));
      int t = tBase + rr;
      float v[8];
#pragma unroll
      for (int j = 0; j < 8; ++j)
        v[j] = (0.5f - (float)acc[i][j] * invS) * gl[j];
      uint2 plo = {packq8k(v[0], v[1]), packq8k(v[2], v[3])};
      *reinterpret_cast<uint2*>(dst + (((size_t)(bI * NH + hl)) * NT + t) * 32 + tx * 2) = plo;
      uint2 phi = {packq8k(v[4], v[5]), packq8k(v[6], v[7])};
      *reinterpret_cast<uint2*>(dst + (((size_t)(bI * NH + hl + 1)) * NT + t) * 32 + tx * 2) = phi;
    }
  } else {
#pragma unroll
    for (int j = 0; j < 8; ++j) {
      int h = hl + (j >> 2);
      int dh = tx * 4 + (j & 3);
      float gj = gl[j];
#pragma unroll
      for (int gI = 0; gI < 2; ++gI) {
        int t0 = tBase + gI * 64 + ty * 4;
        ushort4 o;
        o.x = f16u((0.5f - (float)acc[gI * 4 + 0][j] * invS) * gj);
        o.y = f16u((0.5f - (float)acc[gI * 4 + 1][j] * invS) * gj);
        o.z = f16u((0.5f - (float)acc[gI * 4 + 2][j] * invS) * gj);
        o.w = f16u((0.5f - (float)acc[gI * 4 + 3][j] * invS) * gj);
        *reinterpret_cast<ushort4*>(vh_dm + ((size_t)(bI * NH + h) * 64 + dh) * NT + t0) = o;
      }
    }
  }
}

// ---------------- fused Student-t attention v3 ----------------
// Block: 128 q-rows x (16 kt of 64 k). 256 threads, 4 waves.
// micro-tile 8q x 4k u32; PV via f16 MFMA (wave w owns q rows w*32..+31).
__global__ __launch_bounds__(256, 2) void k_attn3(const unsigned* __restrict__ qq,
                                                  const unsigned* __restrict__ kq,
                                                  const unsigned short* __restrict__ vh,
                                                  const float* __restrict__ gamma,
                                                  const float* __restrict__ rho,
                                                  unsigned short* __restrict__ att_h) {
  const int qt = blockIdx.x;  // 0..7 (128-row q tiles)
  const int h  = blockIdx.y;
  const int b  = blockIdx.z;

  __shared__ unsigned Qs[32][132];  // [du][qrow 0..127]
  __shared__ unsigned Ks[32][68];   // [du][krow 0..63]
  __shared__ unsigned Vt[64][36];   // [d][kpair 0..31]
  __shared__ unsigned Ws[128][37];  // [qrow][kpair f16x2 0..31]
  __shared__ float Inv[128];

  const int tid = threadIdx.x;
  const int lane = tid & 63;
  const int lr = lane & 15, lq = lane >> 4;
  const int w32 = (tid >> 6) * 32;
  const int ty = tid >> 4;   // 0..15 -> q rows ty*8..+7
  const int tx = tid & 15;   // 0..15 -> k rows tx*4..+3

  const float g  = log1pf(expf(gamma[h])) + 1e-4f;
  const float rr = log1pf(expf(rho[h])) + 1e-4f;
  const float gs = g * (1.0f / (64.0f * 8192.0f));

  // stage Q once: 128 rows x 32 u32 (transposed, scalar writes)
  const unsigned* qbase = qq + (((size_t)(b * NH + h)) * NT + qt * 128) * 32;
#pragma unroll
  for (int p = 0; p < 4; ++p) {
    int idx = tid + p * 256;      // 0..1023
    int r = idx >> 3;             // 0..127
    int c4 = (idx & 7) * 4;       // 0..28
    uint4 v = *reinterpret_cast<const uint4*>(qbase + (size_t)r * 32 + c4);
    Qs[c4 + 0][r] = v.x; Qs[c4 + 1][r] = v.y;
    Qs[c4 + 2][r] = v.z; Qs[c4 + 3][r] = v.w;
  }

  f32x4 acc[2][4] = {};
  float wsum[8] = {0.f, 0.f, 0.f, 0.f, 0.f, 0.f, 0.f, 0.f};

  const unsigned* kbh = kq + (((size_t)(b * NH + h)) * NT) * 32;
  const unsigned* v32 = reinterpret_cast<const unsigned*>(vh + ((size_t)(b * NH + h) * 64) * NT);

  for (int kt = 0; kt < 16; ++kt) {
    __syncthreads();  // Q visible (kt=0); prev SAD done with Ks, prev PV done with Vt/Ws
    // stage K (transposed scalar writes) + V (direct b128 copy)
    const unsigned* kbase = kbh + (size_t)(kt * 64) * 32;
#pragma unroll
    for (int p = 0; p < 2; ++p) {
      int idx = tid + p * 256;    // 0..511
      int r = idx >> 3;           // 0..63
      int c4 = (idx & 7) * 4;
      uint4 v = *reinterpret_cast<const uint4*>(kbase + (size_t)r * 32 + c4);
      Ks[c4 + 0][r] = v.x; Ks[c4 + 1][r] = v.y;
      Ks[c4 + 2][r] = v.z; Ks[c4 + 3][r] = v.w;
    }
#pragma unroll
    for (int p = 0; p < 2; ++p) {
      int idx = tid + p * 256;
      int d = idx >> 3;           // 0..63
      int c4 = (idx & 7) * 4;
      uint4 v = *reinterpret_cast<const uint4*>(v32 + (size_t)d * 512 + kt * 32 + c4);
      *reinterpret_cast<uint4*>(&Vt[d][c4]) = v;
    }
    __syncthreads();

    // SAD distances: 8q x 4k per thread
    unsigned dl[8][4] = {};
#pragma unroll 4
    for (int du = 0; du < 32; ++du) {
      uint4 q0 = *reinterpret_cast<const uint4*>(&Qs[du][ty * 8]);
      uint4 q1 = *reinterpret_cast<const uint4*>(&Qs[du][ty * 8 + 4]);
      uint4 kv = *reinterpret_cast<const uint4*>(&Ks[du][tx * 4]);
      unsigned qa[8] = {q0.x, q0.y, q0.z, q0.w, q1.x, q1.y, q1.z, q1.w};
      unsigned ka[4] = {kv.x, kv.y, kv.z, kv.w};
#pragma unroll
      for (int i = 0; i < 8; ++i)
#pragma unroll
        for (int j = 0; j < 4; ++j) dl[i][j] = sad16(qa[i], ka[j], dl[i][j]);
    }

    // Student-t weights -> Ws (b64 writes)
#pragma unroll
    for (int i = 0; i < 8; ++i) {
      float w0[4];
#pragma unroll
      for (int j = 0; j < 4; ++j)
        w0[j] = exp2f(-rr * log2f(fmaf(gs, (float)dl[i][j], 1.0f)));
      wsum[i] += (w0[0] + w0[1]) + (w0[2] + w0[3]);
      uint2 pk = {(unsigned)f16u(w0[0]) | ((unsigned)f16u(w0[1]) << 16),
                  (unsigned)f16u(w0[2]) | ((unsigned)f16u(w0[3]) << 16)};
      *reinterpret_cast<uint2*>(&Ws[ty * 8 + i][tx * 2]) = pk;
    }
    __syncthreads();

    // PV: per wave O[32q x 64d] += W^T V, 16 MFMA
#pragma unroll
    for (int kk = 0; kk < 2; ++kk) {
      f16x8 af[2];
#pragma unroll
      for (int fm = 0; fm < 2; ++fm) {
        uint4 au = *reinterpret_cast<const uint4*>(&Ws[w32 + fm * 16 + lr][kk * 16 + lq * 4]);
        af[fm] = __builtin_bit_cast(f16x8, au);
      }
#pragma unroll
      for (int nt = 0; nt < 4; ++nt) {
        uint4 bu = *reinterpret_cast<const uint4*>(&Vt[nt * 16 + lr][kk * 16 + lq * 4]);
        f16x8 bf = __builtin_bit_cast(f16x8, bu);
#pragma unroll
        for (int fm = 0; fm < 2; ++fm)
          acc[fm][nt] = __builtin_amdgcn_mfma_f32_16x16x32_f16(af[fm], bf, acc[fm][nt], 0, 0, 0);
      }
    }
  }

  // wsum: reduce across the 16 lr lanes; thread rows ty*8+i == w32 + lq*8 + i
#pragma unroll
  for (int i = 0; i < 8; ++i) {
    float s = wsum[i];
    s += __shfl_xor(s, 1, 64);
    s += __shfl_xor(s, 2, 64);
    s += __shfl_xor(s, 4, 64);
    s += __shfl_xor(s, 8, 64);
    if (lr == 0) Inv[w32 + lq * 8 + i] = 1.0f / (s + 1e-6f);
  }
  __syncthreads();

#pragma unroll
  for (int fm = 0; fm < 2; ++fm) {
    float iv[4];
#pragma unroll
    for (int r = 0; r < 4; ++r) iv[r] = Inv[w32 + fm * 16 + lq * 4 + r];
    const size_t rowbase = (size_t)(b * NT + qt * 128 + w32 + fm * 16 + lq * 4);
    const int colbase = h * 64 + lr;
#pragma unroll
    for (int nt = 0; nt < 4; ++nt)
#pragma unroll
      for (int r = 0; r < 4; ++r)
        att_h[(rowbase + r) * NC + colbase + nt * 16] = f16u(acc[fm][nt][r] * iv[r]);
  }
}

// ---------------- f16 MFMA output GEMM (unchanged) ----------------
__global__ __launch_bounds__(256) void k_gemm16(const unsigned short* __restrict__ A,
                                                const unsigned short* __restrict__ Bw,
                                                const float* __restrict__ bias,
                                                float* __restrict__ Out) {
  __shared__ unsigned Ash[128 * 20];
  __shared__ unsigned Bsh[128 * 20];

  const int tid = threadIdx.x;
  const int m0 = blockIdx.y * 128;
  const int n0 = blockIdx.x * 128;
  const int lane = tid & 63;
  const int wv = tid >> 6;
  const int wr = wv >> 1, wc = wv & 1;
  const int lr = lane & 15, lq = lane >> 4;

  f32x4 acc[4][4] = {};

  const unsigned* A32 = reinterpret_cast<const unsigned*>(A);
  const unsigned* B32 = reinterpret_cast<const unsigned*>(Bw);

  for (int ks = 0; ks < 32; ++ks) {
    __syncthreads();
#pragma unroll
    for (int p = 0; p < 2; ++p) {
      int idx = tid + p * 256;
      int r = idx >> 2, q = idx & 3;
      uint4 av = *reinterpret_cast<const uint4*>(A32 + (size_t)(m0 + r) * 512 + ks * 16 + q * 4);
      *reinterpret_cast<uint4*>(&Ash[r * 20 + q * 4]) = av;
      uint4 bv = *reinterpret_cast<const uint4*>(B32 + (size_t)(n0 + r) * 512 + ks * 16 + q * 4);
      *reinterpret_cast<uint4*>(&Bsh[r * 20 + q * 4]) = bv;
    }
    __syncthreads();

    f16x8 af[4], bf[4];
#pragma unroll
    for (int f = 0; f < 4; ++f) {
      uint4 au = *reinterpret_cast<const uint4*>(&Ash[(wr * 64 + f * 16 + lr) * 20 + lq * 4]);
      af[f] = __builtin_bit_cast(f16x8, au);
      uint4 bu = *reinterpret_cast<const uint4*>(&Bsh[(wc * 64 + f * 16 + lr) * 20 + lq * 4]);
      bf[f] = __builtin_bit_cast(f16x8, bu);
    }
#pragma unroll
    for (int fm = 0; fm < 4; ++fm)
#pragma unroll
      for (int fn = 0; fn < 4; ++fn)
        acc[fm][fn] = __builtin_amdgcn_mfma_f32_16x16x32_f16(af[fm], bf[fn], acc[fm][fn], 0, 0, 0);
  }

#pragma unroll
  for (int fn = 0; fn < 4; ++fn) {
    int col = n0 + wc * 64 + fn * 16 + lr;
    float bb = bias[col];
#pragma unroll
    for (int fm = 0; fm < 4; ++fm) {
      int rowb = m0 + wr * 64 + fm * 16 + lq * 4;
#pragma unroll
      for (int r = 0; r < 4; ++r)
        Out[(size_t)(rowb + r) * NC + col] = acc[fm][fn][r] + bb;
    }
  }
}

extern "C" void kernel_launch(void* const* d_in, const int* in_sizes, int n_in,
                              void* d_out, int out_size, void* d_ws, size_t ws_size,
                              hipStream_t stream) {
  (void)in_sizes; (void)n_in; (void)out_size; (void)ws_size;
  const float* x     = (const float*)d_in[0];
  const float* wq_w  = (const float*)d_in[1];
  const float* wq_g  = (const float*)d_in[2];
  const float* wk_w  = (const float*)d_in[3];
  const float* wk_g  = (const float*)d_in[4];
  const float* wv_w  = (const float*)d_in[5];
  const float* wv_g  = (const float*)d_in[6];
  const float* wo_w  = (const float*)d_in[7];
  const float* wo_b  = (const float*)d_in[8];
  const float* gamma = (const float*)d_in[9];
  const float* rho   = (const float*)d_in[10];
  float* out = (float*)d_out;

  // workspace layout:
  unsigned* xq8  = (unsigned*)d_ws;                          // 4MB
  unsigned* wq8  = xq8 + (size_t)MT * KW8;                   // 3MB
  unsigned* qqhm = wq8 + 3ull * NC * KW8;                    // 8MB
  unsigned* kqhm = qqhm + (size_t)NB * NH * NT * 32;         // 8MB
  unsigned short* vhdm = (unsigned short*)(kqhm + (size_t)NB * NH * NT * 32);  // 8MB
  unsigned short* atth = vhdm + (size_t)NB * NH * 64 * NT;   // 8MB
  unsigned short* woh  = atth + (size_t)MT * NC;             // 2MB

  // 1. tanh + u8 quantize; wo -> f16
  k_tanhq8<<<(MT * NC / 8) / 256, 256, 0, stream>>>(x, xq8, MT * NC / 8);
  k_tanhq8<<<(NC * NC / 8) / 256, 256, 0, stream>>>(wq_w, wq8, NC * NC / 8);
  k_tanhq8<<<(NC * NC / 8) / 256, 256, 0, stream>>>(wk_w, wq8 + (size_t)NC * KW8, NC * NC / 8);
  k_tanhq8<<<(NC * NC / 8) / 256, 256, 0, stream>>>(wv_w, wq8 + 2ull * NC * KW8, NC * NC / 8);
  k_cvt16<<<(NC * NC / 8) / 256, 256, 0, stream>>>(wo_w, woh, NC * NC / 8);

  // 2. q/k/v projections via u8 SAD
  k_sadproj8<<<dim3(NC / 128, MT / 128, 3), 256, 0, stream>>>(xq8, wq8, wq_g, wk_g, wv_g,
                                                              qqhm, kqhm, vhdm);

  // 3. fused Student-t attention v3 (128-row q tiles)
  k_attn3<<<dim3(NT / 128, NH, NB), 256, 0, stream>>>(qqhm, kqhm, vhdm, gamma, rho, atth);

  // 4. output projection via f16 MFMA GEMM
  k_gemm16<<<dim3(NC / 128, MT / 128, 1), 256, 0, stream>>>(atth, woh, wo_b, out);
}

// Round 7
// 241.228 us; speedup vs baseline: 1.1251x; 1.1251x over previous
//
#include <hip/hip_runtime.h>
#include <math.h>

// Problem constants: B=4, T=1024, C=1024, H=16, DH=64
namespace {
constexpr int NB  = 4;
constexpr int NT  = 1024;
constexpr int NC  = 1024;
constexpr int NH  = 16;
constexpr int MT  = NB * NT;   // 4096
constexpr int KW8 = NC / 4;    // 256 u32 (u8 x4) per row
}

typedef _Float16 f16x8 __attribute__((ext_vector_type(8)));
typedef float f32x4 __attribute__((ext_vector_type(4)));

__device__ __forceinline__ unsigned sad8(unsigned a, unsigned b, unsigned c) {
  unsigned d;
  asm("v_sad_u8 %0, %1, %2, %3" : "=v"(d) : "v"(a), "v"(b), "v"(c));
  return d;
}

// quantize 4 floats to u8 at 64/unit, offset 128; pack into one u32
__device__ __forceinline__ unsigned packq64(float a, float b, float c, float d) {
  unsigned qa = (unsigned)fminf(fmaxf(fmaf(a, 64.0f, 128.5f), 0.0f), 255.0f);
  unsigned qb = (unsigned)fminf(fmaxf(fmaf(b, 64.0f, 128.5f), 0.0f), 255.0f);
  unsigned qc = (unsigned)fminf(fmaxf(fmaf(c, 64.0f, 128.5f), 0.0f), 255.0f);
  unsigned qd = (unsigned)fminf(fmaxf(fmaf(d, 64.0f, 128.5f), 0.0f), 255.0f);
  return qa | (qb << 8) | (qc << 16) | (qd << 24);
}

__device__ __forceinline__ unsigned short f16u(float x) {
  _Float16 h = (_Float16)x;
  return __builtin_bit_cast(unsigned short, h);
}

// ---------------- tanh + u8 quantize (8 floats -> 2 packed u32) ----------------
__global__ __launch_bounds__(256) void k_tanhq8(const float* __restrict__ in,
                                                unsigned* __restrict__ out, int n8) {
  int i = blockIdx.x * blockDim.x + threadIdx.x;
  if (i >= n8) return;
  const float4* in4 = reinterpret_cast<const float4*>(in);
  float4 v0 = in4[2 * i], v1 = in4[2 * i + 1];
  float t[8] = {v0.x, v0.y, v0.z, v0.w, v1.x, v1.y, v1.z, v1.w};
  unsigned q[8];
#pragma unroll
  for (int j = 0; j < 8; ++j)
    q[j] = (unsigned)fmaf(tanhf(t[j]), 127.5f, 128.0f);  // 0..255
  uint2 o = {q[0] | (q[1] << 8) | (q[2] << 16) | (q[3] << 24),
             q[4] | (q[5] << 8) | (q[6] << 16) | (q[7] << 24)};
  reinterpret_cast<uint2*>(out)[i] = o;
}

// ---------------- fp32 -> f16 convert ----------------
__global__ __launch_bounds__(256) void k_cvt16(const float* __restrict__ in,
                                               unsigned short* __restrict__ out, int n8) {
  int i = blockIdx.x * blockDim.x + threadIdx.x;
  if (i >= n8) return;
  const float4* in4 = reinterpret_cast<const float4*>(in);
  float4 v0 = in4[2 * i], v1 = in4[2 * i + 1];
  ushort4 o0 = {f16u(v0.x), f16u(v0.y), f16u(v0.z), f16u(v0.w)};
  ushort4 o1 = {f16u(v1.x), f16u(v1.y), f16u(v1.z), f16u(v1.w)};
  reinterpret_cast<ushort4*>(out)[2 * i] = o0;
  reinterpret_cast<ushort4*>(out)[2 * i + 1] = o1;
}

// ---------------- u8 SAD projection ----------------
// val[m][n] = (0.5 - sad8(Aq[m],Bq[z][n])/(1024*127.5)) * G[n]
// z=0 -> qq_hm u8-packed head-major [B*H][T][16 u32]
// z=1 -> kq_hm same layout
// z=2 -> vh_dm f16 d-major [B*H][64 d][T]
__global__ __launch_bounds__(256) void k_sadproj8(const unsigned* __restrict__ Aq,
                                                  const unsigned* __restrict__ Bq,
                                                  const float* __restrict__ g0,
                                                  const float* __restrict__ g1,
                                                  const float* __restrict__ g2,
                                                  unsigned* __restrict__ qq_hm,
                                                  unsigned* __restrict__ kq_hm,
                                                  unsigned short* __restrict__ vh_dm) {
  __shared__ unsigned As[16][132];
  __shared__ unsigned Bs[16][132];

  const int tid = threadIdx.x;
  const int z = blockIdx.z;
  const unsigned* Bz = Bq + (size_t)z * NC * KW8;
  const float* G = (z == 0) ? g0 : ((z == 1) ? g1 : g2);
  const int m0 = blockIdx.y * 128;
  const int n0 = blockIdx.x * 128;
  const int ty = tid >> 4;
  const int tx = tid & 15;

  unsigned acc[8][8];
#pragma unroll
  for (int i = 0; i < 8; ++i)
#pragma unroll
    for (int j = 0; j < 8; ++j) acc[i][j] = 0u;

  const int tt = tid & 127;
  const int duq = tt & 3;
  const int r0 = (tt >> 2) * 4;
  const bool doB = (tid >= 128);
  const unsigned* Src = doB ? (Bz + (size_t)n0 * KW8) : (Aq + (size_t)m0 * KW8);

  for (int s = 0; s < 16; ++s) {
    __syncthreads();
    uint4 rv[4];
#pragma unroll
    for (int k2 = 0; k2 < 4; ++k2)
      rv[k2] = *reinterpret_cast<const uint4*>(Src + (size_t)(r0 + k2) * KW8 + s * 16 + duq * 4);
    uint4 w0 = {rv[0].x, rv[1].x, rv[2].x, rv[3].x};
    uint4 w1 = {rv[0].y, rv[1].y, rv[2].y, rv[3].y};
    uint4 w2 = {rv[0].z, rv[1].z, rv[2].z, rv[3].z};
    uint4 w3 = {rv[0].w, rv[1].w, rv[2].w, rv[3].w};
    if (doB) {
      *reinterpret_cast<uint4*>(&Bs[duq * 4 + 0][r0]) = w0;
      *reinterpret_cast<uint4*>(&Bs[duq * 4 + 1][r0]) = w1;
      *reinterpret_cast<uint4*>(&Bs[duq * 4 + 2][r0]) = w2;
      *reinterpret_cast<uint4*>(&Bs[duq * 4 + 3][r0]) = w3;
    } else {
      *reinterpret_cast<uint4*>(&As[duq * 4 + 0][r0]) = w0;
      *reinterpret_cast<uint4*>(&As[duq * 4 + 1][r0]) = w1;
      *reinterpret_cast<uint4*>(&As[duq * 4 + 2][r0]) = w2;
      *reinterpret_cast<uint4*>(&As[duq * 4 + 3][r0]) = w3;
    }
    __syncthreads();

#pragma unroll 4
    for (int du = 0; du < 16; ++du) {
      uint4 alo = *reinterpret_cast<const uint4*>(&As[du][ty * 4]);
      uint4 ahi = *reinterpret_cast<const uint4*>(&As[du][64 + ty * 4]);
      uint4 blo = *reinterpret_cast<const uint4*>(&Bs[du][tx * 4]);
      uint4 bhi = *reinterpret_cast<const uint4*>(&Bs[du][64 + tx * 4]);
      unsigned av[8] = {alo.x, alo.y, alo.z, alo.w, ahi.x, ahi.y, ahi.z, ahi.w};
      unsigned bv[8] = {blo.x, blo.y, blo.z, blo.w, bhi.x, bhi.y, bhi.z, bhi.w};
#pragma unroll
      for (int i = 0; i < 8; ++i)
#pragma unroll
        for (int j = 0; j < 8; ++j) acc[i][j] = sad8(av[i], bv[j], acc[i][j]);
    }
  }

  const float invS = 1.0f / (1024.0f * 127.5f);
  const int bI = m0 >> 10;
  const int tBase = m0 & 1023;
  const int hl = n0 >> 6;
  float gl[8];
#pragma unroll
  for (int j = 0; j < 4; ++j) {
    gl[j]     = G[n0 + tx * 4 + j];
    gl[j + 4] = G[n0 + 64 + tx * 4 + j];
  }

  if (z < 2) {
    unsigned* dst = (z == 0) ? qq_hm : kq_hm;
#pragma unroll
    for (int i = 0; i < 8; ++i) {
      int rr = (i < 4) ? (ty * 4 + i) : (64 + ty * 4 + (i - 4));
      int t = tBase + rr;
      float v[8];
#pragma unroll
      for (int j = 0; j < 8; ++j)
        v[j] = (0.5f - (float)acc[i][j] * invS) * gl[j];
      dst[(((size_t)(bI * NH + hl)) * NT + t) * 16 + tx] = packq64(v[0], v[1], v[2], v[3]);
      dst[(((size_t)(bI * NH + hl + 1)) * NT + t) * 16 + tx] = packq64(v[4], v[5], v[6], v[7]);
    }
  } else {
#pragma unroll
    for (int j = 0; j < 8; ++j) {
      int h = hl + (j >> 2);
      int dh = tx * 4 + (j & 3);
      float gj = gl[j];
#pragma unroll
      for (int gI = 0; gI < 2; ++gI) {
        int t0 = tBase + gI * 64 + ty * 4;
        ushort4 o;
        o.x = f16u((0.5f - (float)acc[gI * 4 + 0][j] * invS) * gj);
        o.y = f16u((0.5f - (float)acc[gI * 4 + 1][j] * invS) * gj);
        o.z = f16u((0.5f - (float)acc[gI * 4 + 2][j] * invS) * gj);
        o.w = f16u((0.5f - (float)acc[gI * 4 + 3][j] * invS) * gj);
        *reinterpret_cast<ushort4*>(vh_dm + ((size_t)(bI * NH + h) * 64 + dh) * NT + t0) = o;
      }
    }
  }
}

// ---------------- fused Student-t attention v4: u8 SAD + f16 MFMA PV ----------------
// Block: 128 q-rows x (16 kt of 64 k). 256 threads, 4 waves.
// Q/K rows are 16 u32 (64 dims as u8). micro-tile 8q x 4k-rows; dist = sad8.
__global__ __launch_bounds__(256, 3) void k_attn4(const unsigned* __restrict__ qq,
                                                  const unsigned* __restrict__ kq,
                                                  const unsigned short* __restrict__ vh,
                                                  const float* __restrict__ gamma,
                                                  const float* __restrict__ rho,
                                                  unsigned short* __restrict__ att_h) {
  const int qt = blockIdx.x;  // 0..7
  const int h  = blockIdx.y;
  const int b  = blockIdx.z;

  __shared__ unsigned Qs[16][132];  // [du][qrow 0..127]
  __shared__ unsigned Ks[16][68];   // [du][krow 0..63]
  __shared__ unsigned Vt[64][36];   // [d][kpair 0..31]
  __shared__ unsigned Ws[128][37];  // [qrow][kpair f16x2]
  __shared__ float Inv[128];

  const int tid = threadIdx.x;
  const int lane = tid & 63;
  const int lr = lane & 15, lq = lane >> 4;
  const int w32 = (tid >> 6) * 32;
  const int ty = tid >> 4;   // 0..15 -> q rows ty*8..+7
  const int tx = tid & 15;   // 0..15 -> k rows tx*4..+3

  const float g  = log1pf(expf(gamma[h])) + 1e-4f;
  const float rr = log1pf(expf(rho[h])) + 1e-4f;
  const float gs = g * (1.0f / (64.0f * 64.0f));

  // stage Q once: 128 rows x 16 u32, transposed
  const unsigned* qbase = qq + (((size_t)(b * NH + h)) * NT + qt * 128) * 16;
#pragma unroll
  for (int p = 0; p < 2; ++p) {
    int idx = tid + p * 256;      // 0..511
    int r = idx >> 2;             // 0..127
    int c4 = (idx & 3) * 4;       // 0,4,8,12
    uint4 v = *reinterpret_cast<const uint4*>(qbase + (size_t)r * 16 + c4);
    Qs[c4 + 0][r] = v.x; Qs[c4 + 1][r] = v.y;
    Qs[c4 + 2][r] = v.z; Qs[c4 + 3][r] = v.w;
  }

  f32x4 acc[2][4] = {};
  float wsum[8] = {0.f, 0.f, 0.f, 0.f, 0.f, 0.f, 0.f, 0.f};

  const unsigned* kbh = kq + (((size_t)(b * NH + h)) * NT) * 16;
  const unsigned* v32 = reinterpret_cast<const unsigned*>(vh + ((size_t)(b * NH + h) * 64) * NT);

  for (int kt = 0; kt < 16; ++kt) {
    __syncthreads();
    // stage K (64 rows x 16 u32, transposed; 1 uint4/thread) + V (b128 copy)
    {
      const unsigned* kbase = kbh + (size_t)(kt * 64) * 16;
      int r = tid >> 2;           // 0..63
      int c4 = (tid & 3) * 4;
      uint4 v = *reinterpret_cast<const uint4*>(kbase + (size_t)r * 16 + c4);
      Ks[c4 + 0][r] = v.x; Ks[c4 + 1][r] = v.y;
      Ks[c4 + 2][r] = v.z; Ks[c4 + 3][r] = v.w;
    }
#pragma unroll
    for (int p = 0; p < 2; ++p) {
      int idx = tid + p * 256;
      int d = idx >> 3;           // 0..63
      int c4 = (idx & 7) * 4;
      uint4 v = *reinterpret_cast<const uint4*>(v32 + (size_t)d * 512 + kt * 32 + c4);
      *reinterpret_cast<uint4*>(&Vt[d][c4]) = v;
    }
    __syncthreads();

    // SAD distances: 8q x 4k per thread, u8 x4 per du
    unsigned dl[8][4] = {};
#pragma unroll 8
    for (int du = 0; du < 16; ++du) {
      uint4 q0 = *reinterpret_cast<const uint4*>(&Qs[du][ty * 8]);
      uint4 q1 = *reinterpret_cast<const uint4*>(&Qs[du][ty * 8 + 4]);
      uint4 kv = *reinterpret_cast<const uint4*>(&Ks[du][tx * 4]);
      unsigned qa[8] = {q0.x, q0.y, q0.z, q0.w, q1.x, q1.y, q1.z, q1.w};
      unsigned ka[4] = {kv.x, kv.y, kv.z, kv.w};
#pragma unroll
      for (int i = 0; i < 8; ++i)
#pragma unroll
        for (int j = 0; j < 4; ++j) dl[i][j] = sad8(qa[i], ka[j], dl[i][j]);
    }

    // Student-t weights -> Ws (b64 writes)
#pragma unroll
    for (int i = 0; i < 8; ++i) {
      float w0[4];
#pragma unroll
      for (int j = 0; j < 4; ++j)
        w0[j] = exp2f(-rr * log2f(fmaf(gs, (float)dl[i][j], 1.0f)));
      wsum[i] += (w0[0] + w0[1]) + (w0[2] + w0[3]);
      uint2 pk = {(unsigned)f16u(w0[0]) | ((unsigned)f16u(w0[1]) << 16),
                  (unsigned)f16u(w0[2]) | ((unsigned)f16u(w0[3]) << 16)};
      *reinterpret_cast<uint2*>(&Ws[ty * 8 + i][tx * 2]) = pk;
    }
    __syncthreads();

    // PV: per wave O[32q x 64d] += W^T V, 16 MFMA
#pragma unroll
    for (int kk = 0; kk < 2; ++kk) {
      f16x8 af[2];
#pragma unroll
      for (int fm = 0; fm < 2; ++fm) {
        uint4 au = *reinterpret_cast<const uint4*>(&Ws[w32 + fm * 16 + lr][kk * 16 + lq * 4]);
        af[fm] = __builtin_bit_cast(f16x8, au);
      }
#pragma unroll
      for (int nt = 0; nt < 4; ++nt) {
        uint4 bu = *reinterpret_cast<const uint4*>(&Vt[nt * 16 + lr][kk * 16 + lq * 4]);
        f16x8 bf = __builtin_bit_cast(f16x8, bu);
#pragma unroll
        for (int fm = 0; fm < 2; ++fm)
          acc[fm][nt] = __builtin_amdgcn_mfma_f32_16x16x32_f16(af[fm], bf, acc[fm][nt], 0, 0, 0);
      }
    }
  }

  // wsum: reduce across the 16 lr lanes; thread rows ty*8+i == w32 + lq*8 + i
#pragma unroll
  for (int i = 0; i < 8; ++i) {
    float s = wsum[i];
    s += __shfl_xor(s, 1, 64);
    s += __shfl_xor(s, 2, 64);
    s += __shfl_xor(s, 4, 64);
    s += __shfl_xor(s, 8, 64);
    if (lr == 0) Inv[w32 + lq * 8 + i] = 1.0f / (s + 1e-6f);
  }
  __syncthreads();

#pragma unroll
  for (int fm = 0; fm < 2; ++fm) {
    float iv[4];
#pragma unroll
    for (int r = 0; r < 4; ++r) iv[r] = Inv[w32 + fm * 16 + lq * 4 + r];
    const size_t rowbase = (size_t)(b * NT + qt * 128 + w32 + fm * 16 + lq * 4);
    const int colbase = h * 64 + lr;
#pragma unroll
    for (int nt = 0; nt < 4; ++nt)
#pragma unroll
      for (int r = 0; r < 4; ++r)
        att_h[(rowbase + r) * NC + colbase + nt * 16] = f16u(acc[fm][nt][r] * iv[r]);
  }
}

// ---------------- f16 MFMA output GEMM (unchanged) ----------------
__global__ __launch_bounds__(256) void k_gemm16(const unsigned short* __restrict__ A,
                                                const unsigned short* __restrict__ Bw,
                                                const float* __restrict__ bias,
                                                float* __restrict__ Out) {
  __shared__ unsigned Ash[128 * 20];
  __shared__ unsigned Bsh[128 * 20];

  const int tid = threadIdx.x;
  const int m0 = blockIdx.y * 128;
  const int n0 = blockIdx.x * 128;
  const int lane = tid & 63;
  const int wv = tid >> 6;
  const int wr = wv >> 1, wc = wv & 1;
  const int lr = lane & 15, lq = lane >> 4;

  f32x4 acc[4][4] = {};

  const unsigned* A32 = reinterpret_cast<const unsigned*>(A);
  const unsigned* B32 = reinterpret_cast<const unsigned*>(Bw);

  for (int ks = 0; ks < 32; ++ks) {
    __syncthreads();
#pragma unroll
    for (int p = 0; p < 2; ++p) {
      int idx = tid + p * 256;
      int r = idx >> 2, q = idx & 3;
      uint4 av = *reinterpret_cast<const uint4*>(A32 + (size_t)(m0 + r) * 512 + ks * 16 + q * 4);
      *reinterpret_cast<uint4*>(&Ash[r * 20 + q * 4]) = av;
      uint4 bv = *reinterpret_cast<const uint4*>(B32 + (size_t)(n0 + r) * 512 + ks * 16 + q * 4);
      *reinterpret_cast<uint4*>(&Bsh[r * 20 + q * 4]) = bv;
    }
    __syncthreads();

    f16x8 af[4], bf[4];
#pragma unroll
    for (int f = 0; f < 4; ++f) {
      uint4 au = *reinterpret_cast<const uint4*>(&Ash[(wr * 64 + f * 16 + lr) * 20 + lq * 4]);
      af[f] = __builtin_bit_cast(f16x8, au);
      uint4 bu = *reinterpret_cast<const uint4*>(&Bsh[(wc * 64 + f * 16 + lr) * 20 + lq * 4]);
      bf[f] = __builtin_bit_cast(f16x8, bu);
    }
#pragma unroll
    for (int fm = 0; fm < 4; ++fm)
#pragma unroll
      for (int fn = 0; fn < 4; ++fn)
        acc[fm][fn] = __builtin_amdgcn_mfma_f32_16x16x32_f16(af[fm], bf[fn], acc[fm][fn], 0, 0, 0);
  }

#pragma unroll
  for (int fn = 0; fn < 4; ++fn) {
    int col = n0 + wc * 64 + fn * 16 + lr;
    float bb = bias[col];
#pragma unroll
    for (int fm = 0; fm < 4; ++fm) {
      int rowb = m0 + wr * 64 + fm * 16 + lq * 4;
#pragma unroll
      for (int r = 0; r < 4; ++r)
        Out[(size_t)(rowb + r) * NC + col] = acc[fm][fn][r] + bb;
    }
  }
}

extern "C" void kernel_launch(void* const* d_in, const int* in_sizes, int n_in,
                              void* d_out, int out_size, void* d_ws, size_t ws_size,
                              hipStream_t stream) {
  (void)in_sizes; (void)n_in; (void)out_size; (void)ws_size;
  const float* x     = (const float*)d_in[0];
  const float* wq_w  = (const float*)d_in[1];
  const float* wq_g  = (const float*)d_in[2];
  const float* wk_w  = (const float*)d_in[3];
  const float* wk_g  = (const float*)d_in[4];
  const float* wv_w  = (const float*)d_in[5];
  const float* wv_g  = (const float*)d_in[6];
  const float* wo_w  = (const float*)d_in[7];
  const float* wo_b  = (const float*)d_in[8];
  const float* gamma = (const float*)d_in[9];
  const float* rho   = (const float*)d_in[10];
  float* out = (float*)d_out;

  // workspace layout:
  unsigned* xq8  = (unsigned*)d_ws;                          // 4MB
  unsigned* wq8  = xq8 + (size_t)MT * KW8;                   // 3MB
  unsigned* qqhm = wq8 + 3ull * NC * KW8;                    // [B*H][T][16] u32 (4MB)
  unsigned* kqhm = qqhm + (size_t)NB * NH * NT * 16;         // 4MB
  unsigned short* vhdm = (unsigned short*)(kqhm + (size_t)NB * NH * NT * 16);  // 8MB
  unsigned short* atth = vhdm + (size_t)NB * NH * 64 * NT;   // 8MB
  unsigned short* woh  = atth + (size_t)MT * NC;             // 2MB

  // 1. tanh + u8 quantize; wo -> f16
  k_tanhq8<<<(MT * NC / 8) / 256, 256, 0, stream>>>(x, xq8, MT * NC / 8);
  k_tanhq8<<<(NC * NC / 8) / 256, 256, 0, stream>>>(wq_w, wq8, NC * NC / 8);
  k_tanhq8<<<(NC * NC / 8) / 256, 256, 0, stream>>>(wk_w, wq8 + (size_t)NC * KW8, NC * NC / 8);
  k_tanhq8<<<(NC * NC / 8) / 256, 256, 0, stream>>>(wv_w, wq8 + 2ull * NC * KW8, NC * NC / 8);
  k_cvt16<<<(NC * NC / 8) / 256, 256, 0, stream>>>(wo_w, woh, NC * NC / 8);

  // 2. q/k/v projections via u8 SAD (q/k emitted as u8-packed, v as f16 d-major)
  k_sadproj8<<<dim3(NC / 128, MT / 128, 3), 256, 0, stream>>>(xq8, wq8, wq_g, wk_g, wv_g,
                                                              qqhm, kqhm, vhdm);

  // 3. fused Student-t attention v4 (u8 SAD dist + f16 MFMA PV)
  k_attn4<<<dim3(NT / 128, NH, NB), 256, 0, stream>>>(qqhm, kqhm, vhdm, gamma, rho, atth);

  // 4. output projection via f16 MFMA GEMM
  k_gemm16<<<dim3(NC / 128, MT / 128, 1), 256, 0, stream>>>(atth, woh, wo_b, out);
}

// Round 8
// 224.506 us; speedup vs baseline: 1.2089x; 1.0745x over previous
//
#include <hip/hip_runtime.h>
#include <math.h>

// Problem constants: B=4, T=1024, C=1024, H=16, DH=64
namespace {
constexpr int NB  = 4;
constexpr int NT  = 1024;
constexpr int NC  = 1024;
constexpr int NH  = 16;
constexpr int MT  = NB * NT;   // 4096
constexpr int KW8 = NC / 4;    // 256 u32 (u8 x4) per row
}

typedef _Float16 f16x8 __attribute__((ext_vector_type(8)));
typedef float f32x4 __attribute__((ext_vector_type(4)));

__device__ __forceinline__ unsigned sad8(unsigned a, unsigned b, unsigned c) {
  unsigned d;
  asm("v_sad_u8 %0, %1, %2, %3" : "=v"(d) : "v"(a), "v"(b), "v"(c));
  return d;
}

// quantize 4 floats to u8 at 64/unit, offset 128; pack into one u32
__device__ __forceinline__ unsigned packq64(float a, float b, float c, float d) {
  unsigned qa = (unsigned)fminf(fmaxf(fmaf(a, 64.0f, 128.5f), 0.0f), 255.0f);
  unsigned qb = (unsigned)fminf(fmaxf(fmaf(b, 64.0f, 128.5f), 0.0f), 255.0f);
  unsigned qc = (unsigned)fminf(fmaxf(fmaf(c, 64.0f, 128.5f), 0.0f), 255.0f);
  unsigned qd = (unsigned)fminf(fmaxf(fmaf(d, 64.0f, 128.5f), 0.0f), 255.0f);
  return qa | (qb << 8) | (qc << 16) | (qd << 24);
}

__device__ __forceinline__ unsigned short f16u(float x) {
  _Float16 h = (_Float16)x;
  return __builtin_bit_cast(unsigned short, h);
}

// ---------------- merged prep: tanh+u8 quantize (x, wq, wk, wv) + wo->f16 ----------------
// 1D grid: [0,2048) x -> xq8 ; [2048,2560) wq ; [2560,3072) wk ; [3072,3584) wv ; [3584,4096) wo cvt
__global__ __launch_bounds__(256) void k_prep(const float* __restrict__ x,
                                              const float* __restrict__ wq,
                                              const float* __restrict__ wk,
                                              const float* __restrict__ wv,
                                              const float* __restrict__ wo,
                                              unsigned* __restrict__ xq8,
                                              unsigned* __restrict__ wq8,
                                              unsigned short* __restrict__ woh) {
  const int bid = blockIdx.x;
  const int tid = threadIdx.x;
  if (bid < 3584) {
    const float* in;
    unsigned* out;
    int local;
    if (bid < 2048)      { in = x;  out = xq8;                         local = bid; }
    else if (bid < 2560) { in = wq; out = wq8;                         local = bid - 2048; }
    else if (bid < 3072) { in = wk; out = wq8 + (size_t)NC * KW8;      local = bid - 2560; }
    else                 { in = wv; out = wq8 + 2ull * NC * KW8;       local = bid - 3072; }
    int i = local * 256 + tid;
    const float4* in4 = reinterpret_cast<const float4*>(in);
    float4 v0 = in4[2 * i], v1 = in4[2 * i + 1];
    float t[8] = {v0.x, v0.y, v0.z, v0.w, v1.x, v1.y, v1.z, v1.w};
    unsigned q[8];
#pragma unroll
    for (int j = 0; j < 8; ++j)
      q[j] = (unsigned)fmaf(tanhf(t[j]), 127.5f, 128.0f);  // 0..255
    uint2 o = {q[0] | (q[1] << 8) | (q[2] << 16) | (q[3] << 24),
               q[4] | (q[5] << 8) | (q[6] << 16) | (q[7] << 24)};
    reinterpret_cast<uint2*>(out)[i] = o;
  } else {
    int i = (bid - 3584) * 256 + tid;
    const float4* in4 = reinterpret_cast<const float4*>(wo);
    float4 v0 = in4[2 * i], v1 = in4[2 * i + 1];
    ushort4 o0 = {f16u(v0.x), f16u(v0.y), f16u(v0.z), f16u(v0.w)};
    ushort4 o1 = {f16u(v1.x), f16u(v1.y), f16u(v1.z), f16u(v1.w)};
    reinterpret_cast<ushort4*>(woh)[2 * i] = o0;
    reinterpret_cast<ushort4*>(woh)[2 * i + 1] = o1;
  }
}

// ---------------- u8 SAD projection, double-buffered LDS ----------------
// val[m][n] = (0.5 - sad8(Aq[m],Bq[z][n])/(1024*127.5)) * G[n]
// z=0 -> qq_hm u8-packed head-major [B*H][T][16 u32]
// z=1 -> kq_hm same layout
// z=2 -> vh_dm f16 d-major [B*H][64 d][T]
__global__ __launch_bounds__(256) void k_sadproj8(const unsigned* __restrict__ Aq,
                                                  const unsigned* __restrict__ Bq,
                                                  const float* __restrict__ g0,
                                                  const float* __restrict__ g1,
                                                  const float* __restrict__ g2,
                                                  unsigned* __restrict__ qq_hm,
                                                  unsigned* __restrict__ kq_hm,
                                                  unsigned short* __restrict__ vh_dm) {
  __shared__ unsigned As[2][16][132];
  __shared__ unsigned Bs[2][16][132];

  const int tid = threadIdx.x;
  const int z = blockIdx.z;
  const unsigned* Bz = Bq + (size_t)z * NC * KW8;
  const float* G = (z == 0) ? g0 : ((z == 1) ? g1 : g2);
  const int m0 = blockIdx.y * 128;
  const int n0 = blockIdx.x * 128;
  const int ty = tid >> 4;
  const int tx = tid & 15;

  unsigned acc[8][8];
#pragma unroll
  for (int i = 0; i < 8; ++i)
#pragma unroll
    for (int j = 0; j < 8; ++j) acc[i][j] = 0u;

  const int tt = tid & 127;
  const int duq = tt & 3;
  const int r0 = (tt >> 2) * 4;
  const bool doB = (tid >= 128);
  const unsigned* Src = doB ? (Bz + (size_t)n0 * KW8) : (Aq + (size_t)m0 * KW8);

  // prologue: stage s=0 into buf0
  {
    uint4 rv[4];
#pragma unroll
    for (int k2 = 0; k2 < 4; ++k2)
      rv[k2] = *reinterpret_cast<const uint4*>(Src + (size_t)(r0 + k2) * KW8 + duq * 4);
    uint4 w0 = {rv[0].x, rv[1].x, rv[2].x, rv[3].x};
    uint4 w1 = {rv[0].y, rv[1].y, rv[2].y, rv[3].y};
    uint4 w2 = {rv[0].z, rv[1].z, rv[2].z, rv[3].z};
    uint4 w3 = {rv[0].w, rv[1].w, rv[2].w, rv[3].w};
    unsigned (*Dst)[132] = doB ? Bs[0] : As[0];
    *reinterpret_cast<uint4*>(&Dst[duq * 4 + 0][r0]) = w0;
    *reinterpret_cast<uint4*>(&Dst[duq * 4 + 1][r0]) = w1;
    *reinterpret_cast<uint4*>(&Dst[duq * 4 + 2][r0]) = w2;
    *reinterpret_cast<uint4*>(&Dst[duq * 4 + 3][r0]) = w3;
  }
  __syncthreads();

  for (int s = 0; s < 16; ++s) {
    const int cur = s & 1;
    // issue next-tile loads early (hide HBM latency under SAD loop)
    uint4 nv[4];
    if (s < 15) {
#pragma unroll
      for (int k2 = 0; k2 < 4; ++k2)
        nv[k2] = *reinterpret_cast<const uint4*>(Src + (size_t)(r0 + k2) * KW8 + (s + 1) * 16 + duq * 4);
    }

#pragma unroll 4
    for (int du = 0; du < 16; ++du) {
      uint4 alo = *reinterpret_cast<const uint4*>(&As[cur][du][ty * 4]);
      uint4 ahi = *reinterpret_cast<const uint4*>(&As[cur][du][64 + ty * 4]);
      uint4 blo = *reinterpret_cast<const uint4*>(&Bs[cur][du][tx * 4]);
      uint4 bhi = *reinterpret_cast<const uint4*>(&Bs[cur][du][64 + tx * 4]);
      unsigned av[8] = {alo.x, alo.y, alo.z, alo.w, ahi.x, ahi.y, ahi.z, ahi.w};
      unsigned bv[8] = {blo.x, blo.y, blo.z, blo.w, bhi.x, bhi.y, bhi.z, bhi.w};
#pragma unroll
      for (int i = 0; i < 8; ++i)
#pragma unroll
        for (int j = 0; j < 8; ++j) acc[i][j] = sad8(av[i], bv[j], acc[i][j]);
    }

    if (s < 15) {
      uint4 w0 = {nv[0].x, nv[1].x, nv[2].x, nv[3].x};
      uint4 w1 = {nv[0].y, nv[1].y, nv[2].y, nv[3].y};
      uint4 w2 = {nv[0].z, nv[1].z, nv[2].z, nv[3].z};
      uint4 w3 = {nv[0].w, nv[1].w, nv[2].w, nv[3].w};
      unsigned (*Dst)[132] = doB ? Bs[cur ^ 1] : As[cur ^ 1];
      *reinterpret_cast<uint4*>(&Dst[duq * 4 + 0][r0]) = w0;
      *reinterpret_cast<uint4*>(&Dst[duq * 4 + 1][r0]) = w1;
      *reinterpret_cast<uint4*>(&Dst[duq * 4 + 2][r0]) = w2;
      *reinterpret_cast<uint4*>(&Dst[duq * 4 + 3][r0]) = w3;
    }
    __syncthreads();
  }

  const float invS = 1.0f / (1024.0f * 127.5f);
  const int bI = m0 >> 10;
  const int tBase = m0 & 1023;
  const int hl = n0 >> 6;
  float gl[8];
#pragma unroll
  for (int j = 0; j < 4; ++j) {
    gl[j]     = G[n0 + tx * 4 + j];
    gl[j + 4] = G[n0 + 64 + tx * 4 + j];
  }

  if (z < 2) {
    unsigned* dst = (z == 0) ? qq_hm : kq_hm;
#pragma unroll
    for (int i = 0; i < 8; ++i) {
      int rr = (i < 4) ? (ty * 4 + i) : (64 + ty * 4 + (i - 4));
      int t = tBase + rr;
      float v[8];
#pragma unroll
      for (int j = 0; j < 8; ++j)
        v[j] = (0.5f - (float)acc[i][j] * invS) * gl[j];
      dst[(((size_t)(bI * NH + hl)) * NT + t) * 16 + tx] = packq64(v[0], v[1], v[2], v[3]);
      dst[(((size_t)(bI * NH + hl + 1)) * NT + t) * 16 + tx] = packq64(v[4], v[5], v[6], v[7]);
    }
  } else {
#pragma unroll
    for (int j = 0; j < 8; ++j) {
      int h = hl + (j >> 2);
      int dh = tx * 4 + (j & 3);
      float gj = gl[j];
#pragma unroll
      for (int gI = 0; gI < 2; ++gI) {
        int t0 = tBase + gI * 64 + ty * 4;
        ushort4 o;
        o.x = f16u((0.5f - (float)acc[gI * 4 + 0][j] * invS) * gj);
        o.y = f16u((0.5f - (float)acc[gI * 4 + 1][j] * invS) * gj);
        o.z = f16u((0.5f - (float)acc[gI * 4 + 2][j] * invS) * gj);
        o.w = f16u((0.5f - (float)acc[gI * 4 + 3][j] * invS) * gj);
        *reinterpret_cast<ushort4*>(vh_dm + ((size_t)(bI * NH + h) * 64 + dh) * NT + t0) = o;
      }
    }
  }
}

// ---------------- fused Student-t attention v5: KVBLK=128, 8q x 8k, u8 SAD + f16 MFMA ----------------
__global__ __launch_bounds__(256, 2) void k_attn5(const unsigned* __restrict__ qq,
                                                  const unsigned* __restrict__ kq,
                                                  const unsigned short* __restrict__ vh,
                                                  const float* __restrict__ gamma,
                                                  const float* __restrict__ rho,
                                                  unsigned short* __restrict__ att_h) {
  const int qt = blockIdx.x;  // 0..7
  const int h  = blockIdx.y;
  const int b  = blockIdx.z;

  __shared__ unsigned Qs[16][132];  // [du][qrow 0..127]
  __shared__ unsigned Ks[16][132];  // [du][split-quad col 0..127]
  __shared__ unsigned Vt[64][68];   // [d][kpair 0..63]
  __shared__ unsigned Ws[128][72];  // [qrow][kpair, XOR-bit2 swizzled]
  __shared__ float Inv[128];

  const int tid = threadIdx.x;
  const int lane = tid & 63;
  const int lr = lane & 15, lq = lane >> 4;
  const int w32 = (tid >> 6) * 32;
  const int ty = tid >> 4;   // 0..15 -> q rows ty*8..+7
  const int tx = tid & 15;   // 0..15 -> k cols tx*8..+7

  const float g  = log1pf(expf(gamma[h])) + 1e-4f;
  const float rr = log1pf(expf(rho[h])) + 1e-4f;
  const float gs = g * (1.0f / (64.0f * 64.0f));

  // stage Q once: 128 rows x 16 u32, transposed
  const unsigned* qbase = qq + (((size_t)(b * NH + h)) * NT + qt * 128) * 16;
#pragma unroll
  for (int p = 0; p < 2; ++p) {
    int idx = tid + p * 256;      // 0..511
    int r = idx >> 2;             // 0..127
    int c4 = (idx & 3) * 4;       // 0,4,8,12
    uint4 v = *reinterpret_cast<const uint4*>(qbase + (size_t)r * 16 + c4);
    Qs[c4 + 0][r] = v.x; Qs[c4 + 1][r] = v.y;
    Qs[c4 + 2][r] = v.z; Qs[c4 + 3][r] = v.w;
  }

  f32x4 acc[2][4] = {};
  float wsum[8] = {0.f, 0.f, 0.f, 0.f, 0.f, 0.f, 0.f, 0.f};

  const unsigned* kbh = kq + (((size_t)(b * NH + h)) * NT) * 16;
  const unsigned* v32 = reinterpret_cast<const unsigned*>(vh + ((size_t)(b * NH + h) * 64) * NT);

  for (int kt = 0; kt < 8; ++kt) {
    __syncthreads();
    // stage K: 128 rows x 16 u32, transposed + split-quad columns
    const unsigned* kbase = kbh + (size_t)(kt * 128) * 16;
#pragma unroll
    for (int p = 0; p < 2; ++p) {
      int idx = tid + p * 256;
      int r = idx >> 2;           // 0..127
      int c4 = (idx & 3) * 4;
      uint4 v = *reinterpret_cast<const uint4*>(kbase + (size_t)r * 16 + c4);
      int cc = ((r & 7) < 4) ? ((r >> 3) * 4 + (r & 3)) : (64 + (r >> 3) * 4 + (r & 3));
      Ks[c4 + 0][cc] = v.x; Ks[c4 + 1][cc] = v.y;
      Ks[c4 + 2][cc] = v.z; Ks[c4 + 3][cc] = v.w;
    }
    // stage V: 64 d x 64 u32 (128 k as f16 pairs)
#pragma unroll
    for (int p = 0; p < 4; ++p) {
      int idx = tid + p * 256;
      int d = idx >> 4;           // 0..63
      int q4 = (idx & 15) * 4;    // 0..60
      uint4 v = *reinterpret_cast<const uint4*>(v32 + (size_t)d * 512 + kt * 64 + q4);
      *reinterpret_cast<uint4*>(&Vt[d][q4]) = v;
    }
    __syncthreads();

    // SAD distances: 8q x 8k per thread
    unsigned dl[8][8] = {};
#pragma unroll 4
    for (int du = 0; du < 16; ++du) {
      uint4 q0 = *reinterpret_cast<const uint4*>(&Qs[du][ty * 8]);
      uint4 q1 = *reinterpret_cast<const uint4*>(&Qs[du][ty * 8 + 4]);
      uint4 k0 = *reinterpret_cast<const uint4*>(&Ks[du][tx * 4]);
      uint4 k1 = *reinterpret_cast<const uint4*>(&Ks[du][64 + tx * 4]);
      unsigned qa[8] = {q0.x, q0.y, q0.z, q0.w, q1.x, q1.y, q1.z, q1.w};
      unsigned ka[8] = {k0.x, k0.y, k0.z, k0.w, k1.x, k1.y, k1.z, k1.w};
#pragma unroll
      for (int i = 0; i < 8; ++i)
#pragma unroll
        for (int j = 0; j < 8; ++j) dl[i][j] = sad8(qa[i], ka[j], dl[i][j]);
    }

    // Student-t weights -> Ws (uint4 writes, XOR-bit2 swizzle by row parity)
#pragma unroll
    for (int i = 0; i < 8; ++i) {
      int qrow = ty * 8 + i;
      float w0[8];
#pragma unroll
      for (int j = 0; j < 8; ++j)
        w0[j] = exp2f(-rr * log2f(fmaf(gs, (float)dl[i][j], 1.0f)));
      wsum[i] += ((w0[0] + w0[1]) + (w0[2] + w0[3])) + ((w0[4] + w0[5]) + (w0[6] + w0[7]));
      uint4 pk;
      pk.x = (unsigned)f16u(w0[0]) | ((unsigned)f16u(w0[1]) << 16);
      pk.y = (unsigned)f16u(w0[2]) | ((unsigned)f16u(w0[3]) << 16);
      pk.z = (unsigned)f16u(w0[4]) | ((unsigned)f16u(w0[5]) << 16);
      pk.w = (unsigned)f16u(w0[6]) | ((unsigned)f16u(w0[7]) << 16);
      *reinterpret_cast<uint4*>(&Ws[qrow][(tx * 4) ^ ((qrow & 1) << 2)]) = pk;
    }
    __syncthreads();

    // PV: per wave O[32q x 64d] += W^T V, 32 MFMA over 4 kk groups
#pragma unroll
    for (int kk = 0; kk < 4; ++kk) {
      f16x8 af[2];
#pragma unroll
      for (int fm = 0; fm < 2; ++fm) {
        int r = w32 + fm * 16 + lr;
        uint4 au = *reinterpret_cast<const uint4*>(&Ws[r][(kk * 16 + lq * 4) ^ ((r & 1) << 2)]);
        af[fm] = __builtin_bit_cast(f16x8, au);
      }
#pragma unroll
      for (int nt = 0; nt < 4; ++nt) {
        uint4 bu = *reinterpret_cast<const uint4*>(&Vt[nt * 16 + lr][kk * 16 + lq * 4]);
        f16x8 bf = __builtin_bit_cast(f16x8, bu);
#pragma unroll
        for (int fm = 0; fm < 2; ++fm)
          acc[fm][nt] = __builtin_amdgcn_mfma_f32_16x16x32_f16(af[fm], bf, acc[fm][nt], 0, 0, 0);
      }
    }
  }

  // wsum: reduce across the 16 lr lanes; thread rows ty*8+i == w32 + lq*8 + i
#pragma unroll
  for (int i = 0; i < 8; ++i) {
    float s = wsum[i];
    s += __shfl_xor(s, 1, 64);
    s += __shfl_xor(s, 2, 64);
    s += __shfl_xor(s, 4, 64);
    s += __shfl_xor(s, 8, 64);
    if (lr == 0) Inv[w32 + lq * 8 + i] = 1.0f / (s + 1e-6f);
  }
  __syncthreads();

#pragma unroll
  for (int fm = 0; fm < 2; ++fm) {
    float iv[4];
#pragma unroll
    for (int r = 0; r < 4; ++r) iv[r] = Inv[w32 + fm * 16 + lq * 4 + r];
    const size_t rowbase = (size_t)(b * NT + qt * 128 + w32 + fm * 16 + lq * 4);
    const int colbase = h * 64 + lr;
#pragma unroll
    for (int nt = 0; nt < 4; ++nt)
#pragma unroll
      for (int r = 0; r < 4; ++r)
        att_h[(rowbase + r) * NC + colbase + nt * 16] = f16u(acc[fm][nt][r] * iv[r]);
  }
}

// ---------------- f16 MFMA output GEMM (unchanged) ----------------
__global__ __launch_bounds__(256) void k_gemm16(const unsigned short* __restrict__ A,
                                                const unsigned short* __restrict__ Bw,
                                                const float* __restrict__ bias,
                                                float* __restrict__ Out) {
  __shared__ unsigned Ash[128 * 20];
  __shared__ unsigned Bsh[128 * 20];

  const int tid = threadIdx.x;
  const int m0 = blockIdx.y * 128;
  const int n0 = blockIdx.x * 128;
  const int lane = tid & 63;
  const int wv = tid >> 6;
  const int wr = wv >> 1, wc = wv & 1;
  const int lr = lane & 15, lq = lane >> 4;

  f32x4 acc[4][4] = {};

  const unsigned* A32 = reinterpret_cast<const unsigned*>(A);
  const unsigned* B32 = reinterpret_cast<const unsigned*>(Bw);

  for (int ks = 0; ks < 32; ++ks) {
    __syncthreads();
#pragma unroll
    for (int p = 0; p < 2; ++p) {
      int idx = tid + p * 256;
      int r = idx >> 2, q = idx & 3;
      uint4 av = *reinterpret_cast<const uint4*>(A32 + (size_t)(m0 + r) * 512 + ks * 16 + q * 4);
      *reinterpret_cast<uint4*>(&Ash[r * 20 + q * 4]) = av;
      uint4 bv = *reinterpret_cast<const uint4*>(B32 + (size_t)(n0 + r) * 512 + ks * 16 + q * 4);
      *reinterpret_cast<uint4*>(&Bsh[r * 20 + q * 4]) = bv;
    }
    __syncthreads();

    f16x8 af[4], bf[4];
#pragma unroll
    for (int f = 0; f < 4; ++f) {
      uint4 au = *reinterpret_cast<const uint4*>(&Ash[(wr * 64 + f * 16 + lr) * 20 + lq * 4]);
      af[f] = __builtin_bit_cast(f16x8, au);
      uint4 bu = *reinterpret_cast<const uint4*>(&Bsh[(wc * 64 + f * 16 + lr) * 20 + lq * 4]);
      bf[f] = __builtin_bit_cast(f16x8, bu);
    }
#pragma unroll
    for (int fm = 0; fm < 4; ++fm)
#pragma unroll
      for (int fn = 0; fn < 4; ++fn)
        acc[fm][fn] = __builtin_amdgcn_mfma_f32_16x16x32_f16(af[fm], bf[fn], acc[fm][fn], 0, 0, 0);
  }

#pragma unroll
  for (int fn = 0; fn < 4; ++fn) {
    int col = n0 + wc * 64 + fn * 16 + lr;
    float bb = bias[col];
#pragma unroll
    for (int fm = 0; fm < 4; ++fm) {
      int rowb = m0 + wr * 64 + fm * 16 + lq * 4;
#pragma unroll
      for (int r = 0; r < 4; ++r)
        Out[(size_t)(rowb + r) * NC + col] = acc[fm][fn][r] + bb;
    }
  }
}

extern "C" void kernel_launch(void* const* d_in, const int* in_sizes, int n_in,
                              void* d_out, int out_size, void* d_ws, size_t ws_size,
                              hipStream_t stream) {
  (void)in_sizes; (void)n_in; (void)out_size; (void)ws_size;
  const float* x     = (const float*)d_in[0];
  const float* wq_w  = (const float*)d_in[1];
  const float* wq_g  = (const float*)d_in[2];
  const float* wk_w  = (const float*)d_in[3];
  const float* wk_g  = (const float*)d_in[4];
  const float* wv_w  = (const float*)d_in[5];
  const float* wv_g  = (const float*)d_in[6];
  const float* wo_w  = (const float*)d_in[7];
  const float* wo_b  = (const float*)d_in[8];
  const float* gamma = (const float*)d_in[9];
  const float* rho   = (const float*)d_in[10];
  float* out = (float*)d_out;

  // workspace layout:
  unsigned* xq8  = (unsigned*)d_ws;                          // 4MB
  unsigned* wq8  = xq8 + (size_t)MT * KW8;                   // 3MB
  unsigned* qqhm = wq8 + 3ull * NC * KW8;                    // [B*H][T][16] u32 (4MB)
  unsigned* kqhm = qqhm + (size_t)NB * NH * NT * 16;         // 4MB
  unsigned short* vhdm = (unsigned short*)(kqhm + (size_t)NB * NH * NT * 16);  // 8MB
  unsigned short* atth = vhdm + (size_t)NB * NH * 64 * NT;   // 8MB
  unsigned short* woh  = atth + (size_t)MT * NC;             // 2MB

  // 1. merged prep: tanh+u8 quantize (x, wq, wk, wv) and wo->f16
  k_prep<<<4096, 256, 0, stream>>>(x, wq_w, wk_w, wv_w, wo_w, xq8, wq8, woh);

  // 2. q/k/v projections via u8 SAD (dbuf LDS)
  k_sadproj8<<<dim3(NC / 128, MT / 128, 3), 256, 0, stream>>>(xq8, wq8, wq_g, wk_g, wv_g,
                                                              qqhm, kqhm, vhdm);

  // 3. fused Student-t attention v5 (KVBLK=128, u8 SAD + f16 MFMA PV)
  k_attn5<<<dim3(NT / 128, NH, NB), 256, 0, stream>>>(qqhm, kqhm, vhdm, gamma, rho, atth);

  // 4. output projection via f16 MFMA GEMM
  k_gemm16<<<dim3(NC / 128, MT / 128, 1), 256, 0, stream>>>(atth, woh, wo_b, out);
}

// Round 9
// 142.372 us; speedup vs baseline: 1.9064x; 1.5769x over previous
//
#include <hip/hip_runtime.h>
#include <math.h>

// Problem constants: B=4, T=1024, C=1024, H=16, DH=64
namespace {
constexpr int NB  = 4;
constexpr int NT  = 1024;
constexpr int NC  = 1024;
constexpr int NH  = 16;
constexpr int MT  = NB * NT;   // 4096
}

typedef _Float16 f16x8 __attribute__((ext_vector_type(8)));
typedef float f32x4 __attribute__((ext_vector_type(4)));
typedef int i32x4 __attribute__((ext_vector_type(4)));

__device__ __forceinline__ unsigned sad8(unsigned a, unsigned b, unsigned c) {
  unsigned d;
  asm("v_sad_u8 %0, %1, %2, %3" : "=v"(d) : "v"(a), "v"(b), "v"(c));
  return d;
}

__device__ __forceinline__ unsigned short f16u(float x) {
  _Float16 h = (_Float16)x;
  return __builtin_bit_cast(unsigned short, h);
}

// ---------------- prep ----------------
// bid < 2048  : x -> sign bytes (+-1 i8 packed) + per-row sum|tanh(x)| (2 rows/block)
// 2048..3584  : wq/wk/wv -> i8 quant at 1024/unit (3072 rows)
// 3584..4096  : wo -> f16
__global__ __launch_bounds__(256) void k_prep(const float* __restrict__ x,
                                              const float* __restrict__ wq,
                                              const float* __restrict__ wk,
                                              const float* __restrict__ wv,
                                              const float* __restrict__ wo,
                                              unsigned* __restrict__ sgnx,
                                              unsigned* __restrict__ wi8,
                                              float* __restrict__ sumax,
                                              unsigned short* __restrict__ woh) {
  const int bid = blockIdx.x;
  const int tid = threadIdx.x;
  if (bid < 2048) {
    int i8o = bid * 256 + tid;   // 8-float chunk; 256 chunks = 2 rows per block
    const float4* in4 = reinterpret_cast<const float4*>(x);
    float4 v0 = in4[2 * i8o], v1 = in4[2 * i8o + 1];
    float t[8] = {v0.x, v0.y, v0.z, v0.w, v1.x, v1.y, v1.z, v1.w};
    unsigned b[8];
    float s = 0.0f;
#pragma unroll
    for (int j = 0; j < 8; ++j) {
      float tv = tanhf(t[j]);
      s += fabsf(tv);
      b[j] = (tv >= 0.0f) ? 0x01u : 0xFFu;
    }
    uint2 o = {b[0] | (b[1] << 8) | (b[2] << 16) | (b[3] << 24),
               b[4] | (b[5] << 8) | (b[6] << 16) | (b[7] << 24)};
    reinterpret_cast<uint2*>(sgnx)[i8o] = o;
    // row-sum: threads 0..127 -> row 2*bid, 128..255 -> row 2*bid+1
#pragma unroll
    for (int off = 32; off > 0; off >>= 1) s += __shfl_down(s, off, 64);
    __shared__ float ws[4];
    if ((tid & 63) == 0) ws[tid >> 6] = s;
    __syncthreads();
    if (tid == 0) {
      sumax[2 * bid]     = ws[0] + ws[1];
      sumax[2 * bid + 1] = ws[2] + ws[3];
    }
  } else if (bid < 3584) {
    const float* in;
    int local;
    if (bid < 2560)      { in = wq; local = bid - 2048; }
    else if (bid < 3072) { in = wk; local = bid - 2560; }
    else                 { in = wv; local = bid - 3072; }
    unsigned* out = wi8 + ((bid < 2560) ? 0 : (bid < 3072) ? (1024 * 256) : (2048 * 256));
    int i8o = local * 256 + tid;
    const float4* in4 = reinterpret_cast<const float4*>(in);
    float4 v0 = in4[2 * i8o], v1 = in4[2 * i8o + 1];
    float t[8] = {v0.x, v0.y, v0.z, v0.w, v1.x, v1.y, v1.z, v1.w};
    unsigned q[8];
#pragma unroll
    for (int j = 0; j < 8; ++j) {
      int qi = __float2int_rn(tanhf(t[j]) * 1024.0f);  // |.| <= ~120, fits i8
      q[j] = (unsigned)qi & 255u;
    }
    uint2 o = {q[0] | (q[1] << 8) | (q[2] << 16) | (q[3] << 24),
               q[4] | (q[5] << 8) | (q[6] << 16) | (q[7] << 24)};
    reinterpret_cast<uint2*>(out)[i8o] = o;
  } else {
    int i = (bid - 3584) * 256 + tid;
    const float4* in4 = reinterpret_cast<const float4*>(wo);
    float4 v0 = in4[2 * i], v1 = in4[2 * i + 1];
    ushort4 o0 = {f16u(v0.x), f16u(v0.y), f16u(v0.z), f16u(v0.w)};
    ushort4 o1 = {f16u(v1.x), f16u(v1.y), f16u(v1.z), f16u(v1.w)};
    reinterpret_cast<ushort4*>(woh)[2 * i] = o0;
    reinterpret_cast<ushort4*>(woh)[2 * i + 1] = o1;
  }
}

// ---------------- sign-trick projection via i8 MFMA ----------------
// G_mn = sum_d sign(xa[m,d]) * wa_i8[n,d]  (i8 GEMM, K=1024)
// sum|xa-wa| ~= sumax[m] - G_mn/1024 ; val = (0.5 - dist)*gain[n]
// A [4096][256 u32] signs, B [3072][256 u32] i8 weights.
// Tile 128x128, 4 waves (2x2), wave = 4x4 of 16x16 tiles, mfma_i32_16x16x64_i8.
// Epilogue packs q/k u8 head-major and v f16 d-major (same layouts as before).
__global__ __launch_bounds__(256, 2) void k_signproj(const unsigned* __restrict__ sgnx,
                                                     const unsigned* __restrict__ wi8,
                                                     const float* __restrict__ sumax,
                                                     const float* __restrict__ g0,
                                                     const float* __restrict__ g1,
                                                     const float* __restrict__ g2,
                                                     unsigned* __restrict__ qq,
                                                     unsigned* __restrict__ kq,
                                                     unsigned short* __restrict__ vh) {
  __shared__ unsigned Ash[128][36];
  __shared__ unsigned Bsh[128][36];

  const int tid = threadIdx.x;
  const int n0 = blockIdx.x * 128;   // 0..3072
  const int m0 = blockIdx.y * 128;   // 0..4096
  const int lane = tid & 63;
  const int wvI = tid >> 6;
  const int wr = wvI >> 1, wc = wvI & 1;
  const int lr = lane & 15, lq = lane >> 4;

  i32x4 acc[4][4] = {};

  const unsigned* A = sgnx + (size_t)m0 * 256;
  const unsigned* Bm = wi8 + (size_t)n0 * 256;

  for (int ks = 0; ks < 8; ++ks) {
    __syncthreads();
#pragma unroll
    for (int p = 0; p < 4; ++p) {
      int idx = tid + p * 256;      // 0..1023
      int r = idx >> 3;             // 0..127
      int q4 = (idx & 7) * 4;       // 0..28
      *reinterpret_cast<uint4*>(&Ash[r][q4]) =
          *reinterpret_cast<const uint4*>(A + (size_t)r * 256 + ks * 32 + q4);
      *reinterpret_cast<uint4*>(&Bsh[r][q4]) =
          *reinterpret_cast<const uint4*>(Bm + (size_t)r * 256 + ks * 32 + q4);
    }
    __syncthreads();

#pragma unroll
    for (int kk = 0; kk < 2; ++kk) {
      i32x4 af[4], bf[4];
#pragma unroll
      for (int f = 0; f < 4; ++f) {
        uint4 au = *reinterpret_cast<const uint4*>(&Ash[wr * 64 + f * 16 + lr][kk * 16 + lq * 4]);
        af[f] = __builtin_bit_cast(i32x4, au);
        uint4 bu = *reinterpret_cast<const uint4*>(&Bsh[wc * 64 + f * 16 + lr][kk * 16 + lq * 4]);
        bf[f] = __builtin_bit_cast(i32x4, bu);
      }
#pragma unroll
      for (int fm = 0; fm < 4; ++fm)
#pragma unroll
        for (int fn = 0; fn < 4; ++fn)
          acc[fm][fn] = __builtin_amdgcn_mfma_i32_16x16x64_i8(af[fm], bf[fn], acc[fm][fn], 0, 0, 0);
    }
  }

  // epilogue
  const int z = n0 >> 10;
  const int nloc = n0 & 1023;
  const int hl = nloc >> 6;
  const int bI = m0 >> 10;
  const int tloc0 = (m0 & 1023) + wr * 64;
  const float* G = (z == 0) ? g0 : ((z == 1) ? g1 : g2);
  const int h = hl + wc;

  float sx[4][4];
#pragma unroll
  for (int fm = 0; fm < 4; ++fm) {
    float4 sv = *reinterpret_cast<const float4*>(sumax + m0 + wr * 64 + fm * 16 + lq * 4);
    sx[fm][0] = sv.x; sx[fm][1] = sv.y; sx[fm][2] = sv.z; sx[fm][3] = sv.w;
  }

  if (z < 2) {
    unsigned* dst = (z == 0) ? qq : kq;
    const int sh = (lr & 3) * 8;
#pragma unroll
    for (int fn = 0; fn < 4; ++fn) {
      float gn = G[nloc + wc * 64 + fn * 16 + lr];
      int txw = (fn * 16 + lr) >> 2;
#pragma unroll
      for (int fm = 0; fm < 4; ++fm) {
#pragma unroll
        for (int reg = 0; reg < 4; ++reg) {
          float accf = (float)acc[fm][fn][reg];
          float dist = (sx[fm][reg] - accf * (1.0f / 1024.0f)) * (1.0f / 1024.0f);
          float val = (0.5f - dist) * gn;
          unsigned p = ((unsigned)fminf(fmaxf(fmaf(val, 64.0f, 128.5f), 0.0f), 255.0f)) << sh;
          p |= __shfl_xor(p, 1, 64);
          p |= __shfl_xor(p, 2, 64);
          if ((lr & 3) == 0) {
            int t = tloc0 + fm * 16 + lq * 4 + reg;
            dst[(((size_t)(bI * NH + h)) * NT + t) * 16 + txw] = p;
          }
        }
      }
    }
  } else {
#pragma unroll
    for (int fn = 0; fn < 4; ++fn) {
      int dh = fn * 16 + lr;
      float gn = G[nloc + wc * 64 + dh];
#pragma unroll
      for (int fm = 0; fm < 4; ++fm) {
        int t0 = tloc0 + fm * 16 + lq * 4;
        ushort4 o;
#pragma unroll
        for (int reg = 0; reg < 4; ++reg) {
          float accf = (float)acc[fm][fn][reg];
          float dist = (sx[fm][reg] - accf * (1.0f / 1024.0f)) * (1.0f / 1024.0f);
          float val = (0.5f - dist) * gn;
          ((unsigned short*)&o)[reg] = f16u(val);
        }
        *reinterpret_cast<ushort4*>(vh + ((size_t)(bI * NH + h) * 64 + dh) * NT + t0) = o;
      }
    }
  }
}

// ---------------- fused Student-t attention v5 (unchanged from R8) ----------------
__global__ __launch_bounds__(256, 2) void k_attn5(const unsigned* __restrict__ qq,
                                                  const unsigned* __restrict__ kq,
                                                  const unsigned short* __restrict__ vh,
                                                  const float* __restrict__ gamma,
                                                  const float* __restrict__ rho,
                                                  unsigned short* __restrict__ att_h) {
  const int qt = blockIdx.x;
  const int h  = blockIdx.y;
  const int b  = blockIdx.z;

  __shared__ unsigned Qs[16][132];
  __shared__ unsigned Ks[16][132];
  __shared__ unsigned Vt[64][68];
  __shared__ unsigned Ws[128][72];
  __shared__ float Inv[128];

  const int tid = threadIdx.x;
  const int lane = tid & 63;
  const int lr = lane & 15, lq = lane >> 4;
  const int w32 = (tid >> 6) * 32;
  const int ty = tid >> 4;
  const int tx = tid & 15;

  const float g  = log1pf(expf(gamma[h])) + 1e-4f;
  const float rr = log1pf(expf(rho[h])) + 1e-4f;
  const float gs = g * (1.0f / (64.0f * 64.0f));

  const unsigned* qbase = qq + (((size_t)(b * NH + h)) * NT + qt * 128) * 16;
#pragma unroll
  for (int p = 0; p < 2; ++p) {
    int idx = tid + p * 256;
    int r = idx >> 2;
    int c4 = (idx & 3) * 4;
    uint4 v = *reinterpret_cast<const uint4*>(qbase + (size_t)r * 16 + c4);
    Qs[c4 + 0][r] = v.x; Qs[c4 + 1][r] = v.y;
    Qs[c4 + 2][r] = v.z; Qs[c4 + 3][r] = v.w;
  }

  f32x4 acc[2][4] = {};
  float wsum[8] = {0.f, 0.f, 0.f, 0.f, 0.f, 0.f, 0.f, 0.f};

  const unsigned* kbh = kq + (((size_t)(b * NH + h)) * NT) * 16;
  const unsigned* v32 = reinterpret_cast<const unsigned*>(vh + ((size_t)(b * NH + h) * 64) * NT);

  for (int kt = 0; kt < 8; ++kt) {
    __syncthreads();
    const unsigned* kbase = kbh + (size_t)(kt * 128) * 16;
#pragma unroll
    for (int p = 0; p < 2; ++p) {
      int idx = tid + p * 256;
      int r = idx >> 2;
      int c4 = (idx & 3) * 4;
      uint4 v = *reinterpret_cast<const uint4*>(kbase + (size_t)r * 16 + c4);
      int cc = ((r & 7) < 4) ? ((r >> 3) * 4 + (r & 3)) : (64 + (r >> 3) * 4 + (r & 3));
      Ks[c4 + 0][cc] = v.x; Ks[c4 + 1][cc] = v.y;
      Ks[c4 + 2][cc] = v.z; Ks[c4 + 3][cc] = v.w;
    }
#pragma unroll
    for (int p = 0; p < 4; ++p) {
      int idx = tid + p * 256;
      int d = idx >> 4;
      int q4 = (idx & 15) * 4;
      uint4 v = *reinterpret_cast<const uint4*>(v32 + (size_t)d * 512 + kt * 64 + q4);
      *reinterpret_cast<uint4*>(&Vt[d][q4]) = v;
    }
    __syncthreads();

    unsigned dl[8][8] = {};
#pragma unroll 4
    for (int du = 0; du < 16; ++du) {
      uint4 q0 = *reinterpret_cast<const uint4*>(&Qs[du][ty * 8]);
      uint4 q1 = *reinterpret_cast<const uint4*>(&Qs[du][ty * 8 + 4]);
      uint4 k0 = *reinterpret_cast<const uint4*>(&Ks[du][tx * 4]);
      uint4 k1 = *reinterpret_cast<const uint4*>(&Ks[du][64 + tx * 4]);
      unsigned qa[8] = {q0.x, q0.y, q0.z, q0.w, q1.x, q1.y, q1.z, q1.w};
      unsigned ka[8] = {k0.x, k0.y, k0.z, k0.w, k1.x, k1.y, k1.z, k1.w};
#pragma unroll
      for (int i = 0; i < 8; ++i)
#pragma unroll
        for (int j = 0; j < 8; ++j) dl[i][j] = sad8(qa[i], ka[j], dl[i][j]);
    }

#pragma unroll
    for (int i = 0; i < 8; ++i) {
      int qrow = ty * 8 + i;
      float w0[8];
#pragma unroll
      for (int j = 0; j < 8; ++j)
        w0[j] = exp2f(-rr * log2f(fmaf(gs, (float)dl[i][j], 1.0f)));
      wsum[i] += ((w0[0] + w0[1]) + (w0[2] + w0[3])) + ((w0[4] + w0[5]) + (w0[6] + w0[7]));
      uint4 pk;
      pk.x = (unsigned)f16u(w0[0]) | ((unsigned)f16u(w0[1]) << 16);
      pk.y = (unsigned)f16u(w0[2]) | ((unsigned)f16u(w0[3]) << 16);
      pk.z = (unsigned)f16u(w0[4]) | ((unsigned)f16u(w0[5]) << 16);
      pk.w = (unsigned)f16u(w0[6]) | ((unsigned)f16u(w0[7]) << 16);
      *reinterpret_cast<uint4*>(&Ws[qrow][(tx * 4) ^ ((qrow & 1) << 2)]) = pk;
    }
    __syncthreads();

#pragma unroll
    for (int kk = 0; kk < 4; ++kk) {
      f16x8 af[2];
#pragma unroll
      for (int fm = 0; fm < 2; ++fm) {
        int r = w32 + fm * 16 + lr;
        uint4 au = *reinterpret_cast<const uint4*>(&Ws[r][(kk * 16 + lq * 4) ^ ((r & 1) << 2)]);
        af[fm] = __builtin_bit_cast(f16x8, au);
      }
#pragma unroll
      for (int nt = 0; nt < 4; ++nt) {
        uint4 bu = *reinterpret_cast<const uint4*>(&Vt[nt * 16 + lr][kk * 16 + lq * 4]);
        f16x8 bf = __builtin_bit_cast(f16x8, bu);
#pragma unroll
        for (int fm = 0; fm < 2; ++fm)
          acc[fm][nt] = __builtin_amdgcn_mfma_f32_16x16x32_f16(af[fm], bf, acc[fm][nt], 0, 0, 0);
      }
    }
  }

#pragma unroll
  for (int i = 0; i < 8; ++i) {
    float s = wsum[i];
    s += __shfl_xor(s, 1, 64);
    s += __shfl_xor(s, 2, 64);
    s += __shfl_xor(s, 4, 64);
    s += __shfl_xor(s, 8, 64);
    if (lr == 0) Inv[w32 + lq * 8 + i] = 1.0f / (s + 1e-6f);
  }
  __syncthreads();

#pragma unroll
  for (int fm = 0; fm < 2; ++fm) {
    float iv[4];
#pragma unroll
    for (int r = 0; r < 4; ++r) iv[r] = Inv[w32 + fm * 16 + lq * 4 + r];
    const size_t rowbase = (size_t)(b * NT + qt * 128 + w32 + fm * 16 + lq * 4);
    const int colbase = h * 64 + lr;
#pragma unroll
    for (int nt = 0; nt < 4; ++nt)
#pragma unroll
      for (int r = 0; r < 4; ++r)
        att_h[(rowbase + r) * NC + colbase + nt * 16] = f16u(acc[fm][nt][r] * iv[r]);
  }
}

// ---------------- f16 MFMA output GEMM (unchanged) ----------------
__global__ __launch_bounds__(256) void k_gemm16(const unsigned short* __restrict__ A,
                                                const unsigned short* __restrict__ Bw,
                                                const float* __restrict__ bias,
                                                float* __restrict__ Out) {
  __shared__ unsigned Ash[128 * 20];
  __shared__ unsigned Bsh[128 * 20];

  const int tid = threadIdx.x;
  const int m0 = blockIdx.y * 128;
  const int n0 = blockIdx.x * 128;
  const int lane = tid & 63;
  const int wv = tid >> 6;
  const int wr = wv >> 1, wc = wv & 1;
  const int lr = lane & 15, lq = lane >> 4;

  f32x4 acc[4][4] = {};

  const unsigned* A32 = reinterpret_cast<const unsigned*>(A);
  const unsigned* B32 = reinterpret_cast<const unsigned*>(Bw);

  for (int ks = 0; ks < 32; ++ks) {
    __syncthreads();
#pragma unroll
    for (int p = 0; p < 2; ++p) {
      int idx = tid + p * 256;
      int r = idx >> 2, q = idx & 3;
      uint4 av = *reinterpret_cast<const uint4*>(A32 + (size_t)(m0 + r) * 512 + ks * 16 + q * 4);
      *reinterpret_cast<uint4*>(&Ash[r * 20 + q * 4]) = av;
      uint4 bv = *reinterpret_cast<const uint4*>(B32 + (size_t)(n0 + r) * 512 + ks * 16 + q * 4);
      *reinterpret_cast<uint4*>(&Bsh[r * 20 + q * 4]) = bv;
    }
    __syncthreads();

    f16x8 af[4], bf[4];
#pragma unroll
    for (int f = 0; f < 4; ++f) {
      uint4 au = *reinterpret_cast<const uint4*>(&Ash[(wr * 64 + f * 16 + lr) * 20 + lq * 4]);
      af[f] = __builtin_bit_cast(f16x8, au);
      uint4 bu = *reinterpret_cast<const uint4*>(&Bsh[(wc * 64 + f * 16 + lr) * 20 + lq * 4]);
      bf[f] = __builtin_bit_cast(f16x8, bu);
    }
#pragma unroll
    for (int fm = 0; fm < 4; ++fm)
#pragma unroll
      for (int fn = 0; fn < 4; ++fn)
        acc[fm][fn] = __builtin_amdgcn_mfma_f32_16x16x32_f16(af[fm], bf[fn], acc[fm][fn], 0, 0, 0);
  }

#pragma unroll
  for (int fn = 0; fn < 4; ++fn) {
    int col = n0 + wc * 64 + fn * 16 + lr;
    float bb = bias[col];
#pragma unroll
    for (int fm = 0; fm < 4; ++fm) {
      int rowb = m0 + wr * 64 + fm * 16 + lq * 4;
#pragma unroll
      for (int r = 0; r < 4; ++r)
        Out[(size_t)(rowb + r) * NC + col] = acc[fm][fn][r] + bb;
    }
  }
}

extern "C" void kernel_launch(void* const* d_in, const int* in_sizes, int n_in,
                              void* d_out, int out_size, void* d_ws, size_t ws_size,
                              hipStream_t stream) {
  (void)in_sizes; (void)n_in; (void)out_size; (void)ws_size;
  const float* x     = (const float*)d_in[0];
  const float* wq_w  = (const float*)d_in[1];
  const float* wq_g  = (const float*)d_in[2];
  const float* wk_w  = (const float*)d_in[3];
  const float* wk_g  = (const float*)d_in[4];
  const float* wv_w  = (const float*)d_in[5];
  const float* wv_g  = (const float*)d_in[6];
  const float* wo_w  = (const float*)d_in[7];
  const float* wo_b  = (const float*)d_in[8];
  const float* gamma = (const float*)d_in[9];
  const float* rho   = (const float*)d_in[10];
  float* out = (float*)d_out;

  // workspace layout:
  unsigned* sgnx = (unsigned*)d_ws;                          // 4096*256 u32 (4MB)
  unsigned* wi8  = sgnx + (size_t)MT * 256;                  // 3072*256 u32 (3MB)
  float* sumax   = (float*)(wi8 + 3072ull * 256);            // 4096 f32 (16KB)
  unsigned* qqhm = (unsigned*)(sumax + MT);                  // [B*H][T][16] u32 (4MB)
  unsigned* kqhm = qqhm + (size_t)NB * NH * NT * 16;         // 4MB
  unsigned short* vhdm = (unsigned short*)(kqhm + (size_t)NB * NH * NT * 16);  // 8MB
  unsigned short* atth = vhdm + (size_t)NB * NH * 64 * NT;   // 8MB
  unsigned short* woh  = atth + (size_t)MT * NC;             // 2MB

  // 1. prep: x -> signs + row-sums; w -> i8; wo -> f16
  k_prep<<<4096, 256, 0, stream>>>(x, wq_w, wk_w, wv_w, wo_w, sgnx, wi8, sumax, woh);

  // 2. q/k/v projections via sign-trick i8 MFMA GEMM (N=3072 covers all three)
  k_signproj<<<dim3(3072 / 128, MT / 128), 256, 0, stream>>>(sgnx, wi8, sumax,
                                                             wq_g, wk_g, wv_g,
                                                             qqhm, kqhm, vhdm);

  // 3. fused Student-t attention v5 (u8 SAD + f16 MFMA PV)
  k_attn5<<<dim3(NT / 128, NH, NB), 256, 0, stream>>>(qqhm, kqhm, vhdm, gamma, rho, atth);

  // 4. output projection via f16 MFMA GEMM
  k_gemm16<<<dim3(NC / 128, MT / 128, 1), 256, 0, stream>>>(atth, woh, wo_b, out);
}